// Round 14
// baseline (47.969 us; speedup 1.0000x reference)
//
#include <hip/hip_runtime.h>
#include <hip/hip_bf16.h>

typedef __attribute__((ext_vector_type(8))) short short8;
typedef __attribute__((ext_vector_type(4))) float f32x4;
typedef __attribute__((ext_vector_type(16))) float f32x16;
typedef __attribute__((ext_vector_type(2))) unsigned uint2e;

__device__ __forceinline__ float elu1(float x) { return x > 0.f ? x : expm1f(x); }
__device__ __forceinline__ unsigned pkbf(float a, float b) {
  return (unsigned)__bfloat16_as_ushort(__float2bfloat16(a)) |
         ((unsigned)__bfloat16_as_ushort(__float2bfloat16(b)) << 16);
}
__device__ __forceinline__ short8 cvt8(float4 a, float4 b, float s) {
  uint4 u = { pkbf(a.x * s, a.y * s), pkbf(a.z * s, a.w * s),
              pkbf(b.x * s, b.y * s), pkbf(b.z * s, b.w * s) };
  union { uint4 u4; short8 s8; } c; c.u4 = u; return c.s8;
}
// truncation pack via v_perm_b32: dst = [a.b2, a.b3, b.b2, b.b3]
__device__ __forceinline__ unsigned pk_perm(float a, float b) {
  return __builtin_amdgcn_perm(__float_as_uint(b), __float_as_uint(a), 0x07060302u);
}

#define VSTRIDE 520   // vts row stride (ushorts): 1040B keeps 16B align; banks lq*4%32 -> conflict-free

// ---------------------------------------------------------------------------
// K1 (fused): LN + QKV(head slice) + attention, one block per (b,h).
//   r13 in-register-P core (32x32x16 MFMAs + permlane32_swap) with 3 fixes:
//   (1) K A-frag load UNCONDITIONAL (broadcast-A: Q's z8 upper half kills
//       k=8..15 garbage) -- no exec juggling in hot loop;
//   (2) vts row stride 512 -> 520 ushorts: kills the 8-way bank conflict on
//       every V-frag read (stride-1024B rows all hit one bank group);
//   (3) explicit next-iter register prefetch (cn=(c+1)&15, branch-free).
//   LDS ~24KB; 512 thr / 8 waves; wave owns 64 q-rows (2 q-sets of 32).
// ---------------------------------------------------------------------------
__global__ __launch_bounds__(512, 4) void k_fattn(
    const float* __restrict__ xp, const float* __restrict__ ln_g, const float* __restrict__ ln_b,
    const float* __restrict__ Wqkv, const float* __restrict__ bqkv,
    ushort* __restrict__ obf)
{
  __shared__ ushort qlds[512 * 8];        // Q rows [s][d], 8KB
  __shared__ ushort klds[512 * 8];        // K rows [s][d], 8KB
  __shared__ ushort vts[8 * VSTRIDE];     // V^T [d][s], padded rows, ~8.1KB

  const float sc = 0.35355339059327373f * 1.4426950408889634f;  // 1/sqrt(8)*log2(e)
  int tid = threadIdx.x, w = tid >> 6, lane = tid & 63;
  int g = lane >> 4, qr = lane & 15;
  int bh = blockIdx.x, b = bh >> 2, h = bh & 3;
  const short8 z8 = {0, 0, 0, 0, 0, 0, 0, 0};

  // ---- weight fragments (once per block) ----
  int wrow = (qr < 8) ? (h * 8 + qr) : (32 + h * 8 + qr - 8);
  float qsc = (qr < 8) ? sc : 1.f;
  const float4* wr = (const float4*)(Wqkv + wrow * 32 + g * 8);
  short8 wqk = cvt8(wr[0], wr[1], qsc);
  short8 wv = z8;
  if (qr < 8) {
    const float4* vr = (const float4*)(Wqkv + (64 + h * 8 + qr) * 32 + g * 8);
    wv = cvt8(vr[0], vr[1], 1.f);
  }
  f32x4 bqk, bv;
  #pragma unroll
  for (int r = 0; r < 4; ++r) {
    bqk[r] = (g < 2) ? bqkv[h * 8 + g * 4 + r] * sc : bqkv[32 + h * 8 + (g - 2) * 4 + r];
    bv[r]  = (g < 2) ? bqkv[64 + h * 8 + g * 4 + r] : 0.f;
  }
  const float4* lg4 = (const float4*)(ln_g + g * 8);
  const float4* lb4 = (const float4*)(ln_b + g * 8);
  float4 ga = lg4[0], gb2 = lg4[1], ba = lb4[0], bb2 = lb4[1];

  // ---- staging: 4 groups of 16 rows per wave (verified r6-r13) ----
  #pragma unroll
  for (int i = 0; i < 4; ++i) {
    int rloc = w * 64 + i * 16 + qr;
    const float4* xr = (const float4*)(xp + (b * 512 + rloc) * 32 + g * 8);
    float4 x0 = xr[0], x1 = xr[1];
    float s1 = x0.x + x0.y + x0.z + x0.w + x1.x + x1.y + x1.z + x1.w;
    float s2 = x0.x*x0.x + x0.y*x0.y + x0.z*x0.z + x0.w*x0.w
             + x1.x*x1.x + x1.y*x1.y + x1.z*x1.z + x1.w*x1.w;
    s1 += __shfl_xor(s1, 16); s1 += __shfl_xor(s1, 32);
    s2 += __shfl_xor(s2, 16); s2 += __shfl_xor(s2, 32);
    float mu = s1 * 0.03125f;
    float rs = rsqrtf(s2 * 0.03125f - mu * mu + 1e-5f);
    float4 n0 = { (x0.x-mu)*rs*ga.x+ba.x, (x0.y-mu)*rs*ga.y+ba.y,
                  (x0.z-mu)*rs*ga.z+ba.z, (x0.w-mu)*rs*ga.w+ba.w };
    float4 n1 = { (x1.x-mu)*rs*gb2.x+bb2.x, (x1.y-mu)*rs*gb2.y+bb2.y,
                  (x1.z-mu)*rs*gb2.z+bb2.z, (x1.w-mu)*rs*gb2.w+bb2.w };
    short8 bx = cvt8(n0, n1, 1.f);   // B-frag: xn[s=qr][e=g*8+j]

    f32x4 cqk = __builtin_amdgcn_mfma_f32_16x16x32_bf16(wqk, bx, bqk, 0, 0, 0);
    f32x4 cv  = __builtin_amdgcn_mfma_f32_16x16x32_bf16(wv,  bx, bv,  0, 0, 0);
    uint2 o2 = { pkbf(cqk[0], cqk[1]), pkbf(cqk[2], cqk[3]) };
    ushort* dst = (g < 2) ? qlds : klds;
    *(uint2*)(dst + rloc * 8 + (g & 1) * 4) = o2;
    if (g < 2) {
      #pragma unroll
      for (int r = 0; r < 4; ++r)
        vts[(g * 4 + r) * VSTRIDE + rloc] = __bfloat16_as_ushort(__float2bfloat16(cv[r]));
    }
  }
  __syncthreads();

  // ---- attention: 32x32 MFMAs, in-register P ----
  const short8 one8 = {(short)0x3F80, (short)0x3F80, (short)0x3F80, (short)0x3F80,
                       (short)0x3F80, (short)0x3F80, (short)0x3F80, (short)0x3F80};
  const f32x16 z16 = {};
  int half = lane >> 5, lq = lane & 31;
  bool vload = (lq < 8);
  short8 vconst = (lq == 8) ? one8 : z8;     // loop-invariant fallback
  const ushort* vrow = vts + lq * VSTRIDE + half * 8;

  // Q B-frags (one read per q-set, hoisted; upper half MUST be z8 -- this is
  // what makes the unconditional K load correct)
  short8 qfA = (half == 0) ? *(const short8*)(qlds + (w * 64 + lq) * 8) : z8;
  short8 qfB = (half == 0) ? *(const short8*)(qlds + (w * 64 + 32 + lq) * 8) : z8;
  f32x16 accA = {}, accB = {};

#define QSTEP(QF, ACC) do {                                                          \
    f32x16 s = __builtin_amdgcn_mfma_f32_32x32x16_bf16(kf, QF, z16, 0, 0, 0);        \
    unsigned w0 = pk_perm(__builtin_amdgcn_exp2f(s[0]),  __builtin_amdgcn_exp2f(s[1]));  \
    unsigned w1 = pk_perm(__builtin_amdgcn_exp2f(s[2]),  __builtin_amdgcn_exp2f(s[3]));  \
    unsigned w2 = pk_perm(__builtin_amdgcn_exp2f(s[4]),  __builtin_amdgcn_exp2f(s[5]));  \
    unsigned w3 = pk_perm(__builtin_amdgcn_exp2f(s[6]),  __builtin_amdgcn_exp2f(s[7]));  \
    unsigned w4 = pk_perm(__builtin_amdgcn_exp2f(s[8]),  __builtin_amdgcn_exp2f(s[9]));  \
    unsigned w5 = pk_perm(__builtin_amdgcn_exp2f(s[10]), __builtin_amdgcn_exp2f(s[11])); \
    unsigned w6 = pk_perm(__builtin_amdgcn_exp2f(s[12]), __builtin_amdgcn_exp2f(s[13])); \
    unsigned w7 = pk_perm(__builtin_amdgcn_exp2f(s[14]), __builtin_amdgcn_exp2f(s[15])); \
    uint2e r02 = __builtin_amdgcn_permlane32_swap(w0, w2, false, false);             \
    uint2e r13 = __builtin_amdgcn_permlane32_swap(w1, w3, false, false);             \
    uint2e r46 = __builtin_amdgcn_permlane32_swap(w4, w6, false, false);             \
    uint2e r57 = __builtin_amdgcn_permlane32_swap(w5, w7, false, false);             \
    union { uint4 u; short8 s8; } pA, pB;                                            \
    pA.u = (uint4){r02.x, r13.x, r02.y, r13.y};                                      \
    pB.u = (uint4){r46.x, r57.x, r46.y, r57.y};                                      \
    ACC = __builtin_amdgcn_mfma_f32_32x32x16_bf16(vfA, pA.s8, ACC, 0, 0, 0);         \
    ACC = __builtin_amdgcn_mfma_f32_32x32x16_bf16(vfB, pB.s8, ACC, 0, 0, 0);         \
  } while (0)

  // prefetch c=0 (K load unconditional: broadcast across halves)
  short8 kf  = *(const short8*)(klds + lq * 8);
  short8 vfA = vload ? *(const short8*)(vrow)      : vconst;
  short8 vfB = vload ? *(const short8*)(vrow + 16) : vconst;

  for (int c = 0; c < 16; ++c) {
    int cn = (c + 1) & 15;   // branch-free; c=15 prefetch harmlessly rereads c=0
    short8 kf_n  = *(const short8*)(klds + (cn * 32 + lq) * 8);
    short8 vfA_n = vload ? *(const short8*)(vrow + cn * 32)      : vconst;
    short8 vfB_n = vload ? *(const short8*)(vrow + cn * 32 + 16) : vconst;
    QSTEP(qfA, accA);
    QSTEP(qfB, accB);
    kf = kf_n; vfA = vfA_n; vfB = vfB_n;
  }
#undef QSTEP

  // ---- normalize + store ----
  // acc: D[d'][qrow=lq], regs 0-3 = d half*4+0..3; lower-lane reg 4 = row 8
  // = row-sum.  All 64 lanes store.
  #pragma unroll
  for (int qs = 0; qs < 2; ++qs) {
    f32x16 acc = qs ? accB : accA;
    float rl = 1.f / __shfl(acc[4], lq, 64);   // sum lives in lower lane lq
    int rowg = bh * 512 + w * 64 + qs * 32 + lq;
    uint2 o2 = { pkbf(acc[0] * rl, acc[1] * rl), pkbf(acc[2] * rl, acc[3] * rl) };
    *(uint2*)((unsigned*)obf + rowg * 4 + half * 2) = o2;
  }
}

// ---------------------------------------------------------------------------
// K2: oproj+residual into LDS (XOR-swizzled float4 slots), then the per-b
//     tail.  Layers 0..10 are dead code (qo-attention with a single key
//     ignores its query input); only layer 11 matters.
//     One block per b, 512 thr / 8 waves.  (unchanged)
// ---------------------------------------------------------------------------
__global__ __launch_bounds__(512) void k_final(
    const ushort* __restrict__ obf, const float* __restrict__ xp,
    const float* __restrict__ Wo, const float* __restrict__ bo,
    const float* __restrict__ xo,
    const float* __restrict__ oW0, const float* __restrict__ ob0,
    const float* __restrict__ oW1, const float* __restrict__ ob1,
    const float* __restrict__ oW2, const float* __restrict__ ob2,
    const float* __restrict__ oW3, const float* __restrict__ ob3,
    const float* __restrict__ qoW, const float* __restrict__ qob,
    const float* __restrict__ qoWo, const float* __restrict__ qobo,
    const float* __restrict__ qpW, const float* __restrict__ qpb,
    const float* __restrict__ qpWo, const float* __restrict__ qpbo,
    const float* __restrict__ fW1, const float* __restrict__ fb1,
    const float* __restrict__ fW2, const float* __restrict__ fb2,
    const float* __restrict__ gW, const float* __restrict__ gb,
    const float* __restrict__ hW, const float* __restrict__ hb,
    float* __restrict__ out)
{
  __shared__ float4 imgl[512 * 8];      // img[b] in swizzled float4 slots, 64KB
  __shared__ float p[4][512];
  __shared__ float partial[16][4][32];
  __shared__ float buf1[80], buf2[64];
  __shared__ float emb[32], qbar[32], qh[32], u[4][32], cc4[4], lsum[4], ctx4[4][32], t32[32], o32[32];
  int b = blockIdx.x, tid = threadIdx.x;
  int w = tid >> 6, lane = tid & 63, g = lane >> 4, qr = lane & 15;

  // ---- oproj + residual -> imgl (8 waves x 4 iters x 2 MFMAs) ----
  {
    short8 wa[2]; f32x4 bc2[2];
    #pragma unroll
    for (int t = 0; t < 2; ++t) {
      const float4* wrr = (const float4*)(Wo + (t * 16 + qr) * 32 + g * 8);
      wa[t] = cvt8(wrr[0], wrr[1], 1.f);
      const float4 bb = *(const float4*)(bo + t * 16 + g * 4);
      bc2[t] = (f32x4){bb.x, bb.y, bb.z, bb.w};
    }
    #pragma unroll
    for (int j = 0; j < 4; ++j) {
      int rloc = j * 128 + w * 16 + qr;
      short8 ob = *(const short8*)(obf + ((b * 4 + g) * 512 + rloc) * 8);
      #pragma unroll
      for (int t = 0; t < 2; ++t) {
        f32x4 ct = __builtin_amdgcn_mfma_f32_16x16x32_bf16(wa[t], ob, bc2[t], 0, 0, 0);
        int e4 = t * 4 + g;
        float4 xv = *(const float4*)(xp + (b * 512 + rloc) * 32 + e4 * 4);
        imgl[rloc * 8 + (e4 ^ (rloc & 7))] =
            (float4){ xv.x + ct[0], xv.y + ct[1], xv.z + ct[2], xv.w + ct[3] };
      }
    }
  }
  __syncthreads();

  // ---- frozen omic encoder ----
  if (tid < 80) buf1[tid] = xo[b * 80 + tid];
  __syncthreads();
  if (tid < 64) { float a = ob0[tid]; const float* wgt = oW0 + tid * 80;
    for (int e = 0; e < 80; ++e) a += buf1[e] * wgt[e]; buf2[tid] = elu1(a); }
  __syncthreads();
  if (tid < 48) { float a = ob1[tid]; const float* wgt = oW1 + tid * 64;
    for (int e = 0; e < 64; ++e) a += buf2[e] * wgt[e]; buf1[tid] = elu1(a); }
  __syncthreads();
  if (tid < 32) { float a = ob2[tid]; const float* wgt = oW2 + tid * 48;
    for (int e = 0; e < 48; ++e) a += buf1[e] * wgt[e]; buf2[tid] = elu1(a); }
  __syncthreads();
  if (tid < 32) { float a = ob3[tid]; const float* wgt = oW3 + tid * 32;
    for (int e = 0; e < 32; ++e) a += buf2[e] * wgt[e]; emb[tid] = elu1(a); }
  __syncthreads();

  // ---- qo attention (kv-len 1 => V,O proj only) ----
  if (tid < 32) { float a = qob[64 + tid]; const float* wgt = qoW + (64 + tid) * 32;
    for (int e = 0; e < 32; ++e) a += emb[e] * wgt[e]; t32[tid] = a; }
  __syncthreads();
  if (tid < 32) { float a = qobo[tid]; const float* wgt = qoWo + tid * 32;
    for (int e = 0; e < 32; ++e) a += t32[e] * wgt[e]; qbar[tid] = a; }
  __syncthreads();

  // ---- qp attention, single query row (folded) ----
  if (tid < 32) { float a = qpb[tid]; const float* wgt = qpW + tid * 32;
    for (int e = 0; e < 32; ++e) a += qbar[e] * wgt[e]; qh[tid] = a; }
  __syncthreads();
  if (tid < 128) {
    int hh = tid >> 5, e = tid & 31;
    float a = 0.f;
    #pragma unroll
    for (int d = 0; d < 8; ++d) a += qh[hh * 8 + d] * qpW[(32 + hh * 8 + d) * 32 + e];
    u[hh][e] = a;
    if (e == 0) { float c2 = 0.f; for (int d = 0; d < 8; ++d) c2 += qh[hh * 8 + d] * qpb[32 + hh * 8 + d]; cc4[hh] = c2; }
  }
  __syncthreads();

  #pragma unroll
  for (int j = 0; j < 4; ++j) {
    int idx = tid + j * 512; int hh = idx >> 9, kk = idx & 511;
    const float* uh = u[hh];
    float a = cc4[hh];
    #pragma unroll
    for (int e4 = 0; e4 < 8; ++e4) {
      float4 t = imgl[kk * 8 + (e4 ^ (kk & 7))];
      a += uh[e4 * 4] * t.x + uh[e4 * 4 + 1] * t.y + uh[e4 * 4 + 2] * t.z + uh[e4 * 4 + 3] * t.w;
    }
    p[hh][kk] = __builtin_amdgcn_exp2f(fminf(a * 0.51006979f, 115.f));
  }
  __syncthreads();
  if (tid < 256) {
    int ww = tid >> 6, ln2 = tid & 63;
    float a = 0.f;
    for (int kk = ln2; kk < 512; kk += 64) a += p[ww][kk];
    #pragma unroll
    for (int m = 32; m >= 1; m >>= 1) a += __shfl_xor(a, m, 64);
    if (ln2 == 0) lsum[ww] = 1.f / a;
  }
  {
    int e = tid & 31, ch = tid >> 5;     // 16 chunks of 32 kidx
    float a0 = 0.f, a1 = 0.f, a2 = 0.f, a3 = 0.f;
    for (int kk = ch * 32; kk < ch * 32 + 32; ++kk) {
      float val = ((const float*)&imgl[kk * 8 + ((e >> 2) ^ (kk & 7))])[e & 3];
      a0 += p[0][kk] * val; a1 += p[1][kk] * val; a2 += p[2][kk] * val; a3 += p[3][kk] * val;
    }
    partial[ch][0][e] = a0; partial[ch][1][e] = a1; partial[ch][2][e] = a2; partial[ch][3][e] = a3;
  }
  __syncthreads();
  if (tid < 128) {
    int hh = tid >> 5, e = tid & 31;
    float a = 0.f;
    #pragma unroll
    for (int ch = 0; ch < 16; ++ch) a += partial[ch][hh][e];
    ctx4[hh][e] = a * lsum[hh];
  }
  __syncthreads();
  if (tid < 32) { int hh = tid >> 3;
    float a = qpb[64 + tid]; const float* wgt = qpW + (64 + tid) * 32;
    for (int e = 0; e < 32; ++e) a += ctx4[hh][e] * wgt[e]; o32[tid] = a; }
  __syncthreads();
  if (tid < 32) { float a = qpbo[tid]; const float* wgt = qpWo + tid * 32;
    for (int e = 0; e < 32; ++e) a += o32[e] * wgt[e]; t32[tid] = a; }
  __syncthreads();

  // ---- FFN (no residual) ----
  if (tid < 32) { float a = fb1[tid]; const float* wgt = fW1 + tid * 32;
    for (int e = 0; e < 32; ++e) a += t32[e] * wgt[e]; o32[tid] = fmaxf(a, 0.f); }
  __syncthreads();
  if (tid < 32) { float a = fb2[tid]; const float* wgt = fW2 + tid * 32;
    for (int e = 0; e < 32; ++e) a += o32[e] * wgt[e]; qbar[tid] = a; }
  __syncthreads();

  // ---- heads ----
  if (tid < 32) out[b * 32 + tid] = qbar[tid];
  if (tid == 0) {
    float g0 = gb[0], g1 = gb[1], g2 = gb[2];
    for (int e = 0; e < 32; ++e) { float f = qbar[e]; g0 += f * gW[e]; g1 += f * gW[32 + e]; g2 += f * gW[64 + e]; }
    float m = fmaxf(g0, fmaxf(g1, g2));
    float lse = m + logf(expf(g0 - m) + expf(g1 - m) + expf(g2 - m));
    float* og = out + 4096;
    og[b * 3 + 0] = g0 - lse; og[b * 3 + 1] = g1 - lse; og[b * 3 + 2] = g2 - lse;
    float hz = hb[0];
    for (int e = 0; e < 32; ++e) hz += qbar[e] * hW[e];
    out[4480 + b] = 1.f / (1.f + expf(-hz)) * 6.f - 3.f;
  }
}

extern "C" void kernel_launch(void* const* d_in, const int* in_sizes, int n_in,
                              void* d_out, int out_size, void* d_ws, size_t ws_size,
                              hipStream_t stream) {
  const float* x_omic = (const float*)d_in[0];
  const float* x_path = (const float*)d_in[1];
  const float* oW0 = (const float*)d_in[2];  const float* ob0 = (const float*)d_in[3];
  const float* oW1 = (const float*)d_in[4];  const float* ob1 = (const float*)d_in[5];
  const float* oW2 = (const float*)d_in[6];  const float* ob2 = (const float*)d_in[7];
  const float* oW3 = (const float*)d_in[8];  const float* ob3 = (const float*)d_in[9];
  const float* ln_g = (const float*)d_in[10]; const float* ln_b = (const float*)d_in[11];
  const float* cW  = (const float*)d_in[12]; const float* cb  = (const float*)d_in[13];
  const float* cWo = (const float*)d_in[14]; const float* cbo = (const float*)d_in[15];
  const float* qoW = (const float*)d_in[16]; const float* qob = (const float*)d_in[17];
  const float* qoWo = (const float*)d_in[18]; const float* qobo = (const float*)d_in[19];
  const float* qpW = (const float*)d_in[20]; const float* qpb = (const float*)d_in[21];
  const float* qpWo = (const float*)d_in[22]; const float* qpbo = (const float*)d_in[23];
  const float* fW1 = (const float*)d_in[24]; const float* fb1 = (const float*)d_in[25];
  const float* fW2 = (const float*)d_in[26]; const float* fb2 = (const float*)d_in[27];
  // d_in[28] = Qs — provably unused
  const float* gW = (const float*)d_in[29]; const float* gb = (const float*)d_in[30];
  const float* hW = (const float*)d_in[31]; const float* hb = (const float*)d_in[32];

  float* out = (float*)d_out;
  ushort* obf = (ushort*)d_ws;   // 4 MB bf16 [B,H,S,8] — only surviving intermediate

  const int L = 11;  // layers 0..10 are dead code
  k_fattn<<<512, 512, 0, stream>>>(x_path, ln_g, ln_b, cW, cb, obf);
  k_final<<<128, 512, 0, stream>>>(obf, x_path, cWo, cbo, x_omic,
      oW0, ob0, oW1, ob1, oW2, ob2, oW3, ob3,
      qoW + L * 96 * 32, qob + L * 96, qoWo + L * 32 * 32, qobo + L * 32,
      qpW + L * 96 * 32, qpb + L * 96, qpWo + L * 32 * 32, qpbo + L * 32,
      fW1 + L * 32 * 32, fb1 + L * 32, fW2 + L * 32 * 32, fb2 + L * 32,
      gW, gb, hW, hb, out);
}

// Round 15
// 47.260 us; speedup vs baseline: 1.0150x; 1.0150x over previous
//
#include <hip/hip_runtime.h>
#include <hip/hip_bf16.h>

typedef __attribute__((ext_vector_type(8))) short short8;
typedef __attribute__((ext_vector_type(4))) float f32x4;
typedef __attribute__((ext_vector_type(16))) float f32x16;
typedef __attribute__((ext_vector_type(2))) unsigned uint2e;

__device__ __forceinline__ float elu1(float x) { return x > 0.f ? x : expm1f(x); }
__device__ __forceinline__ unsigned pkbf(float a, float b) {
  return (unsigned)__bfloat16_as_ushort(__float2bfloat16(a)) |
         ((unsigned)__bfloat16_as_ushort(__float2bfloat16(b)) << 16);
}
__device__ __forceinline__ short8 cvt8(float4 a, float4 b, float s) {
  uint4 u = { pkbf(a.x * s, a.y * s), pkbf(a.z * s, a.w * s),
              pkbf(b.x * s, b.y * s), pkbf(b.z * s, b.w * s) };
  union { uint4 u4; short8 s8; } c; c.u4 = u; return c.s8;
}
// truncation pack via v_perm_b32: dst = [a.b2, a.b3, b.b2, b.b3]
__device__ __forceinline__ unsigned pk_perm(float a, float b) {
  return __builtin_amdgcn_perm(__float_as_uint(b), __float_as_uint(a), 0x07060302u);
}

// ---------------------------------------------------------------------------
// K1 (fused): LN + QKV(head slice) + attention, one block per (b,h).
//   ROUND-13 EXACT (best measured: 47.3us total, absmax 1.22e-4).
//   In-register-P attention core: 32x32x16 MFMAs; S^T = mfma(K,Q); exp2 ->
//   trunc-pack -> permlane32_swap pairs build the PV B-frag in-register.
//   No P LDS buffer.  Row-sum free via ones-row d=8 of the PV A-frag.
//   LDS 24KB (Q 8 + K 8 + V^T 8); 512 thr / 8 waves; wave owns 64 q-rows.
// ---------------------------------------------------------------------------
__global__ __launch_bounds__(512, 4) void k_fattn(
    const float* __restrict__ xp, const float* __restrict__ ln_g, const float* __restrict__ ln_b,
    const float* __restrict__ Wqkv, const float* __restrict__ bqkv,
    ushort* __restrict__ obf)
{
  __shared__ ushort qlds[512 * 8];        // Q rows [s][d], 8KB
  __shared__ ushort klds[512 * 8];        // K rows [s][d], 8KB
  __shared__ ushort vts[8 * 512];         // V^T [d][s], 8KB

  const float sc = 0.35355339059327373f * 1.4426950408889634f;  // 1/sqrt(8)*log2(e)
  int tid = threadIdx.x, w = tid >> 6, lane = tid & 63;
  int g = lane >> 4, qr = lane & 15;
  int bh = blockIdx.x, b = bh >> 2, h = bh & 3;
  const short8 z8 = {0, 0, 0, 0, 0, 0, 0, 0};

  // ---- weight fragments (once per block) ----
  int wrow = (qr < 8) ? (h * 8 + qr) : (32 + h * 8 + qr - 8);
  float qsc = (qr < 8) ? sc : 1.f;
  const float4* wr = (const float4*)(Wqkv + wrow * 32 + g * 8);
  short8 wqk = cvt8(wr[0], wr[1], qsc);
  short8 wv = z8;
  if (qr < 8) {
    const float4* vr = (const float4*)(Wqkv + (64 + h * 8 + qr) * 32 + g * 8);
    wv = cvt8(vr[0], vr[1], 1.f);
  }
  f32x4 bqk, bv;
  #pragma unroll
  for (int r = 0; r < 4; ++r) {
    bqk[r] = (g < 2) ? bqkv[h * 8 + g * 4 + r] * sc : bqkv[32 + h * 8 + (g - 2) * 4 + r];
    bv[r]  = (g < 2) ? bqkv[64 + h * 8 + g * 4 + r] : 0.f;
  }
  const float4* lg4 = (const float4*)(ln_g + g * 8);
  const float4* lb4 = (const float4*)(ln_b + g * 8);
  float4 ga = lg4[0], gb2 = lg4[1], ba = lb4[0], bb2 = lb4[1];

  // ---- staging: 4 groups of 16 rows per wave (verified r6-r13) ----
  #pragma unroll
  for (int i = 0; i < 4; ++i) {
    int rloc = w * 64 + i * 16 + qr;
    const float4* xr = (const float4*)(xp + (b * 512 + rloc) * 32 + g * 8);
    float4 x0 = xr[0], x1 = xr[1];
    float s1 = x0.x + x0.y + x0.z + x0.w + x1.x + x1.y + x1.z + x1.w;
    float s2 = x0.x*x0.x + x0.y*x0.y + x0.z*x0.z + x0.w*x0.w
             + x1.x*x1.x + x1.y*x1.y + x1.z*x1.z + x1.w*x1.w;
    s1 += __shfl_xor(s1, 16); s1 += __shfl_xor(s1, 32);
    s2 += __shfl_xor(s2, 16); s2 += __shfl_xor(s2, 32);
    float mu = s1 * 0.03125f;
    float rs = rsqrtf(s2 * 0.03125f - mu * mu + 1e-5f);
    float4 n0 = { (x0.x-mu)*rs*ga.x+ba.x, (x0.y-mu)*rs*ga.y+ba.y,
                  (x0.z-mu)*rs*ga.z+ba.z, (x0.w-mu)*rs*ga.w+ba.w };
    float4 n1 = { (x1.x-mu)*rs*gb2.x+bb2.x, (x1.y-mu)*rs*gb2.y+bb2.y,
                  (x1.z-mu)*rs*gb2.z+bb2.z, (x1.w-mu)*rs*gb2.w+bb2.w };
    short8 bx = cvt8(n0, n1, 1.f);   // B-frag: xn[s=qr][e=g*8+j]

    f32x4 cqk = __builtin_amdgcn_mfma_f32_16x16x32_bf16(wqk, bx, bqk, 0, 0, 0);
    f32x4 cv  = __builtin_amdgcn_mfma_f32_16x16x32_bf16(wv,  bx, bv,  0, 0, 0);
    uint2 o2 = { pkbf(cqk[0], cqk[1]), pkbf(cqk[2], cqk[3]) };
    ushort* dst = (g < 2) ? qlds : klds;
    *(uint2*)(dst + rloc * 8 + (g & 1) * 4) = o2;
    if (g < 2) {
      #pragma unroll
      for (int r = 0; r < 4; ++r)
        vts[(g * 4 + r) * 512 + rloc] = __bfloat16_as_ushort(__float2bfloat16(cv[r]));
    }
  }
  __syncthreads();

  // ---- attention: 32x32 MFMAs, in-register P ----
  const short8 one8 = {(short)0x3F80, (short)0x3F80, (short)0x3F80, (short)0x3F80,
                       (short)0x3F80, (short)0x3F80, (short)0x3F80, (short)0x3F80};
  const f32x16 z16 = {};
  int half = lane >> 5, lq = lane & 31;

  // Q B-frags (one read per q-set, hoisted for the whole kernel)
  short8 qfA = (half == 0) ? *(const short8*)(qlds + (w * 64 + lq) * 8) : z8;
  short8 qfB = (half == 0) ? *(const short8*)(qlds + (w * 64 + 32 + lq) * 8) : z8;
  f32x16 accA = {}, accB = {};

#define QSTEP(QF, ACC) do {                                                          \
    f32x16 s = __builtin_amdgcn_mfma_f32_32x32x16_bf16(kf, QF, z16, 0, 0, 0);        \
    unsigned w0 = pk_perm(__builtin_amdgcn_exp2f(s[0]),  __builtin_amdgcn_exp2f(s[1]));  \
    unsigned w1 = pk_perm(__builtin_amdgcn_exp2f(s[2]),  __builtin_amdgcn_exp2f(s[3]));  \
    unsigned w2 = pk_perm(__builtin_amdgcn_exp2f(s[4]),  __builtin_amdgcn_exp2f(s[5]));  \
    unsigned w3 = pk_perm(__builtin_amdgcn_exp2f(s[6]),  __builtin_amdgcn_exp2f(s[7]));  \
    unsigned w4 = pk_perm(__builtin_amdgcn_exp2f(s[8]),  __builtin_amdgcn_exp2f(s[9]));  \
    unsigned w5 = pk_perm(__builtin_amdgcn_exp2f(s[10]), __builtin_amdgcn_exp2f(s[11])); \
    unsigned w6 = pk_perm(__builtin_amdgcn_exp2f(s[12]), __builtin_amdgcn_exp2f(s[13])); \
    unsigned w7 = pk_perm(__builtin_amdgcn_exp2f(s[14]), __builtin_amdgcn_exp2f(s[15])); \
    uint2e r02 = __builtin_amdgcn_permlane32_swap(w0, w2, false, false);             \
    uint2e r13 = __builtin_amdgcn_permlane32_swap(w1, w3, false, false);             \
    uint2e r46 = __builtin_amdgcn_permlane32_swap(w4, w6, false, false);             \
    uint2e r57 = __builtin_amdgcn_permlane32_swap(w5, w7, false, false);             \
    union { uint4 u; short8 s8; } pA, pB;                                            \
    pA.u = (uint4){r02.x, r13.x, r02.y, r13.y};                                      \
    pB.u = (uint4){r46.x, r57.x, r46.y, r57.y};                                      \
    ACC = __builtin_amdgcn_mfma_f32_32x32x16_bf16(vfA, pA.s8, ACC, 0, 0, 0);         \
    ACC = __builtin_amdgcn_mfma_f32_32x32x16_bf16(vfB, pB.s8, ACC, 0, 0, 0);         \
  } while (0)

  for (int c = 0; c < 16; ++c) {
    // K A-frag: A[kidx=lq][d=half*8+j]; upper half (d 8..15) = zeros
    short8 kf = (half == 0) ? *(const short8*)(klds + (c * 32 + lq) * 8) : z8;
    // V A-frags: A[d=lq][k=half*8+j]; d=8 row = ones (free row-sum), d>8 = 0
    const ushort* vbase = vts + lq * 512 + c * 32 + half * 8;
    short8 vfA = (lq < 8) ? *(const short8*)(vbase)      : (lq == 8 ? one8 : z8);
    short8 vfB = (lq < 8) ? *(const short8*)(vbase + 16) : (lq == 8 ? one8 : z8);
    QSTEP(qfA, accA);
    QSTEP(qfB, accB);
  }
#undef QSTEP

  // ---- normalize + store ----
  // acc: D[d'][qrow=lq], regs 0-3 = d half*4+0..3; lower-lane reg 4 = row 8
  // = row-sum.  All 64 lanes store.
  #pragma unroll
  for (int qs = 0; qs < 2; ++qs) {
    f32x16 acc = qs ? accB : accA;
    float rl = 1.f / __shfl(acc[4], lq, 64);   // sum lives in lower lane lq
    int rowg = bh * 512 + w * 64 + qs * 32 + lq;
    uint2 o2 = { pkbf(acc[0] * rl, acc[1] * rl), pkbf(acc[2] * rl, acc[3] * rl) };
    *(uint2*)((unsigned*)obf + rowg * 4 + half * 2) = o2;
  }
}

// ---------------------------------------------------------------------------
// K2: oproj+residual into LDS (XOR-swizzled float4 slots), then the per-b
//     tail.  Layers 0..10 are dead code (qo-attention with a single key
//     ignores its query input); only layer 11 matters.
//     One block per b, 512 thr / 8 waves.  (unchanged)
// ---------------------------------------------------------------------------
__global__ __launch_bounds__(512) void k_final(
    const ushort* __restrict__ obf, const float* __restrict__ xp,
    const float* __restrict__ Wo, const float* __restrict__ bo,
    const float* __restrict__ xo,
    const float* __restrict__ oW0, const float* __restrict__ ob0,
    const float* __restrict__ oW1, const float* __restrict__ ob1,
    const float* __restrict__ oW2, const float* __restrict__ ob2,
    const float* __restrict__ oW3, const float* __restrict__ ob3,
    const float* __restrict__ qoW, const float* __restrict__ qob,
    const float* __restrict__ qoWo, const float* __restrict__ qobo,
    const float* __restrict__ qpW, const float* __restrict__ qpb,
    const float* __restrict__ qpWo, const float* __restrict__ qpbo,
    const float* __restrict__ fW1, const float* __restrict__ fb1,
    const float* __restrict__ fW2, const float* __restrict__ fb2,
    const float* __restrict__ gW, const float* __restrict__ gb,
    const float* __restrict__ hW, const float* __restrict__ hb,
    float* __restrict__ out)
{
  __shared__ float4 imgl[512 * 8];      // img[b] in swizzled float4 slots, 64KB
  __shared__ float p[4][512];
  __shared__ float partial[16][4][32];
  __shared__ float buf1[80], buf2[64];
  __shared__ float emb[32], qbar[32], qh[32], u[4][32], cc4[4], lsum[4], ctx4[4][32], t32[32], o32[32];
  int b = blockIdx.x, tid = threadIdx.x;
  int w = tid >> 6, lane = tid & 63, g = lane >> 4, qr = lane & 15;

  // ---- oproj + residual -> imgl (8 waves x 4 iters x 2 MFMAs) ----
  {
    short8 wa[2]; f32x4 bc2[2];
    #pragma unroll
    for (int t = 0; t < 2; ++t) {
      const float4* wrr = (const float4*)(Wo + (t * 16 + qr) * 32 + g * 8);
      wa[t] = cvt8(wrr[0], wrr[1], 1.f);
      const float4 bb = *(const float4*)(bo + t * 16 + g * 4);
      bc2[t] = (f32x4){bb.x, bb.y, bb.z, bb.w};
    }
    #pragma unroll
    for (int j = 0; j < 4; ++j) {
      int rloc = j * 128 + w * 16 + qr;
      short8 ob = *(const short8*)(obf + ((b * 4 + g) * 512 + rloc) * 8);
      #pragma unroll
      for (int t = 0; t < 2; ++t) {
        f32x4 ct = __builtin_amdgcn_mfma_f32_16x16x32_bf16(wa[t], ob, bc2[t], 0, 0, 0);
        int e4 = t * 4 + g;
        float4 xv = *(const float4*)(xp + (b * 512 + rloc) * 32 + e4 * 4);
        imgl[rloc * 8 + (e4 ^ (rloc & 7))] =
            (float4){ xv.x + ct[0], xv.y + ct[1], xv.z + ct[2], xv.w + ct[3] };
      }
    }
  }
  __syncthreads();

  // ---- frozen omic encoder ----
  if (tid < 80) buf1[tid] = xo[b * 80 + tid];
  __syncthreads();
  if (tid < 64) { float a = ob0[tid]; const float* wgt = oW0 + tid * 80;
    for (int e = 0; e < 80; ++e) a += buf1[e] * wgt[e]; buf2[tid] = elu1(a); }
  __syncthreads();
  if (tid < 48) { float a = ob1[tid]; const float* wgt = oW1 + tid * 64;
    for (int e = 0; e < 64; ++e) a += buf2[e] * wgt[e]; buf1[tid] = elu1(a); }
  __syncthreads();
  if (tid < 32) { float a = ob2[tid]; const float* wgt = oW2 + tid * 48;
    for (int e = 0; e < 48; ++e) a += buf1[e] * wgt[e]; buf2[tid] = elu1(a); }
  __syncthreads();
  if (tid < 32) { float a = ob3[tid]; const float* wgt = oW3 + tid * 32;
    for (int e = 0; e < 32; ++e) a += buf2[e] * wgt[e]; emb[tid] = elu1(a); }
  __syncthreads();

  // ---- qo attention (kv-len 1 => V,O proj only) ----
  if (tid < 32) { float a = qob[64 + tid]; const float* wgt = qoW + (64 + tid) * 32;
    for (int e = 0; e < 32; ++e) a += emb[e] * wgt[e]; t32[tid] = a; }
  __syncthreads();
  if (tid < 32) { float a = qobo[tid]; const float* wgt = qoWo + tid * 32;
    for (int e = 0; e < 32; ++e) a += t32[e] * wgt[e]; qbar[tid] = a; }
  __syncthreads();

  // ---- qp attention, single query row (folded) ----
  if (tid < 32) { float a = qpb[tid]; const float* wgt = qpW + tid * 32;
    for (int e = 0; e < 32; ++e) a += qbar[e] * wgt[e]; qh[tid] = a; }
  __syncthreads();
  if (tid < 128) {
    int hh = tid >> 5, e = tid & 31;
    float a = 0.f;
    #pragma unroll
    for (int d = 0; d < 8; ++d) a += qh[hh * 8 + d] * qpW[(32 + hh * 8 + d) * 32 + e];
    u[hh][e] = a;
    if (e == 0) { float c2 = 0.f; for (int d = 0; d < 8; ++d) c2 += qh[hh * 8 + d] * qpb[32 + hh * 8 + d]; cc4[hh] = c2; }
  }
  __syncthreads();

  #pragma unroll
  for (int j = 0; j < 4; ++j) {
    int idx = tid + j * 512; int hh = idx >> 9, kk = idx & 511;
    const float* uh = u[hh];
    float a = cc4[hh];
    #pragma unroll
    for (int e4 = 0; e4 < 8; ++e4) {
      float4 t = imgl[kk * 8 + (e4 ^ (kk & 7))];
      a += uh[e4 * 4] * t.x + uh[e4 * 4 + 1] * t.y + uh[e4 * 4 + 2] * t.z + uh[e4 * 4 + 3] * t.w;
    }
    p[hh][kk] = __builtin_amdgcn_exp2f(fminf(a * 0.51006979f, 115.f));
  }
  __syncthreads();
  if (tid < 256) {
    int ww = tid >> 6, ln2 = tid & 63;
    float a = 0.f;
    for (int kk = ln2; kk < 512; kk += 64) a += p[ww][kk];
    #pragma unroll
    for (int m = 32; m >= 1; m >>= 1) a += __shfl_xor(a, m, 64);
    if (ln2 == 0) lsum[ww] = 1.f / a;
  }
  {
    int e = tid & 31, ch = tid >> 5;     // 16 chunks of 32 kidx
    float a0 = 0.f, a1 = 0.f, a2 = 0.f, a3 = 0.f;
    for (int kk = ch * 32; kk < ch * 32 + 32; ++kk) {
      float val = ((const float*)&imgl[kk * 8 + ((e >> 2) ^ (kk & 7))])[e & 3];
      a0 += p[0][kk] * val; a1 += p[1][kk] * val; a2 += p[2][kk] * val; a3 += p[3][kk] * val;
    }
    partial[ch][0][e] = a0; partial[ch][1][e] = a1; partial[ch][2][e] = a2; partial[ch][3][e] = a3;
  }
  __syncthreads();
  if (tid < 128) {
    int hh = tid >> 5, e = tid & 31;
    float a = 0.f;
    #pragma unroll
    for (int ch = 0; ch < 16; ++ch) a += partial[ch][hh][e];
    ctx4[hh][e] = a * lsum[hh];
  }
  __syncthreads();
  if (tid < 32) { int hh = tid >> 3;
    float a = qpb[64 + tid]; const float* wgt = qpW + (64 + tid) * 32;
    for (int e = 0; e < 32; ++e) a += ctx4[hh][e] * wgt[e]; o32[tid] = a; }
  __syncthreads();
  if (tid < 32) { float a = qpbo[tid]; const float* wgt = qpWo + tid * 32;
    for (int e = 0; e < 32; ++e) a += o32[e] * wgt[e]; t32[tid] = a; }
  __syncthreads();

  // ---- FFN (no residual) ----
  if (tid < 32) { float a = fb1[tid]; const float* wgt = fW1 + tid * 32;
    for (int e = 0; e < 32; ++e) a += t32[e] * wgt[e]; o32[tid] = fmaxf(a, 0.f); }
  __syncthreads();
  if (tid < 32) { float a = fb2[tid]; const float* wgt = fW2 + tid * 32;
    for (int e = 0; e < 32; ++e) a += o32[e] * wgt[e]; qbar[tid] = a; }
  __syncthreads();

  // ---- heads ----
  if (tid < 32) out[b * 32 + tid] = qbar[tid];
  if (tid == 0) {
    float g0 = gb[0], g1 = gb[1], g2 = gb[2];
    for (int e = 0; e < 32; ++e) { float f = qbar[e]; g0 += f * gW[e]; g1 += f * gW[32 + e]; g2 += f * gW[64 + e]; }
    float m = fmaxf(g0, fmaxf(g1, g2));
    float lse = m + logf(expf(g0 - m) + expf(g1 - m) + expf(g2 - m));
    float* og = out + 4096;
    og[b * 3 + 0] = g0 - lse; og[b * 3 + 1] = g1 - lse; og[b * 3 + 2] = g2 - lse;
    float hz = hb[0];
    for (int e = 0; e < 32; ++e) hz += qbar[e] * hW[e];
    out[4480 + b] = 1.f / (1.f + expf(-hz)) * 6.f - 3.f;
  }
}

extern "C" void kernel_launch(void* const* d_in, const int* in_sizes, int n_in,
                              void* d_out, int out_size, void* d_ws, size_t ws_size,
                              hipStream_t stream) {
  const float* x_omic = (const float*)d_in[0];
  const float* x_path = (const float*)d_in[1];
  const float* oW0 = (const float*)d_in[2];  const float* ob0 = (const float*)d_in[3];
  const float* oW1 = (const float*)d_in[4];  const float* ob1 = (const float*)d_in[5];
  const float* oW2 = (const float*)d_in[6];  const float* ob2 = (const float*)d_in[7];
  const float* oW3 = (const float*)d_in[8];  const float* ob3 = (const float*)d_in[9];
  const float* ln_g = (const float*)d_in[10]; const float* ln_b = (const float*)d_in[11];
  const float* cW  = (const float*)d_in[12]; const float* cb  = (const float*)d_in[13];
  const float* cWo = (const float*)d_in[14]; const float* cbo = (const float*)d_in[15];
  const float* qoW = (const float*)d_in[16]; const float* qob = (const float*)d_in[17];
  const float* qoWo = (const float*)d_in[18]; const float* qobo = (const float*)d_in[19];
  const float* qpW = (const float*)d_in[20]; const float* qpb = (const float*)d_in[21];
  const float* qpWo = (const float*)d_in[22]; const float* qpbo = (const float*)d_in[23];
  const float* fW1 = (const float*)d_in[24]; const float* fb1 = (const float*)d_in[25];
  const float* fW2 = (const float*)d_in[26]; const float* fb2 = (const float*)d_in[27];
  // d_in[28] = Qs — provably unused
  const float* gW = (const float*)d_in[29]; const float* gb = (const float*)d_in[30];
  const float* hW = (const float*)d_in[31]; const float* hb = (const float*)d_in[32];

  float* out = (float*)d_out;
  ushort* obf = (ushort*)d_ws;   // 4 MB bf16 [B,H,S,8] — only surviving intermediate

  const int L = 11;  // layers 0..10 are dead code
  k_fattn<<<512, 512, 0, stream>>>(x_path, ln_g, ln_b, cW, cb, obf);
  k_final<<<128, 512, 0, stream>>>(obf, x_path, cWo, cbo, x_omic,
      oW0, ob0, oW1, ob1, oW2, ob2, oW3, ob3,
      qoW + L * 96 * 32, qob + L * 96, qoWo + L * 32 * 32, qobo + L * 32,
      qpW + L * 96 * 32, qpb + L * 96, qpWo + L * 32 * 32, qpbo + L * 32,
      fW1 + L * 32 * 32, fb1 + L * 32, fW2 + L * 32 * 32, fb2 + L * 32,
      gW, gb, hW, hb, out);
}